// Round 10
// baseline (237.010 us; speedup 1.0000x reference)
//
#include <hip/hip_runtime.h>
#include <hip/hip_bf16.h>

#define B_ 64
#define T_ 128
#define E_ 256
#define H_ 256
#define OW_ 512   // output row width = 2*H (elements)
#define LP 264    // LDS bf16 row pitch for row-major staging tiles (elements)
#define MAGIC 0x5AD00000u

typedef unsigned short ushort_t;
typedef __attribute__((ext_vector_type(8))) short bf16x8;   // 8 bf16 = 4 VGPRs
typedef __attribute__((ext_vector_type(4))) float f32x4;    // 4 f32 acc

// Workgroup barrier WITHOUT the compiler's vmcnt(0) drain (validated r7/r8).
#define LGKM_BARRIER() asm volatile("s_waitcnt lgkmcnt(0)\n\ts_barrier" ::: "memory")
// Keep weight fragments loop-carried (r12).
#define PIN_FRAG(x) asm volatile("" : "+v"(x))

__device__ __forceinline__ ushort_t f2bf(float f) {
    unsigned int x = __float_as_uint(f);
    unsigned int r = x + 0x7FFFu + ((x >> 16) & 1u);
    return (ushort_t)(r >> 16);
}
__device__ __forceinline__ float fast_tanh(float x) {
    float e = __expf(2.0f * x);
    return 1.0f - 2.0f * __builtin_amdgcn_rcpf(e + 1.0f);
}
__device__ __forceinline__ bf16x8 load_bfrag(const float* W, const float* M,
                                             size_t base) {
    float4 a = *(const float4*)(W + base);
    float4 b = *(const float4*)(W + base + 4);
    if (M) {
        float4 ma = *(const float4*)(M + base);
        float4 mb = *(const float4*)(M + base + 4);
        a.x *= ma.x; a.y *= ma.y; a.z *= ma.z; a.w *= ma.w;
        b.x *= mb.x; b.y *= mb.y; b.z *= mb.z; b.w *= mb.w;
    }
    union { bf16x8 v; ushort_t u[8]; } r;
    r.u[0] = f2bf(a.x); r.u[1] = f2bf(a.y); r.u[2] = f2bf(a.z); r.u[3] = f2bf(a.w);
    r.u[4] = f2bf(b.x); r.u[5] = f2bf(b.y); r.u[6] = f2bf(b.z); r.u[7] = f2bf(b.w);
    return r.v;
}

// Fragment-major LDS A-layout for hb (r9-verified): element (r,k) at
//   off = (k>>5)*512 + ((k>>3)&3)*128 + r*8 + (k&7)
// Reader lane L reads frag kk as b128 at element L*8 + kk*512 (linear,
// conflict-free). Pad-row lanes ((l15&2)!=0; C rows discarded) broadcast.
__device__ __forceinline__ int a_off(int r, int k) {
    return ((k >> 5) << 9) + (((k >> 3) & 3) << 7) + (r << 3) + (k & 7);
}

// ---------------------------------------------------------------------------
// r18 = r17 pipeline (producer -> fuser -> consumer, proj0 in-dispatch) with
// the xf workspace ELIMINATED. Evidence: total-minus-scan gap is 65us at
// ws=64B (r14) vs 99us at ws=8.4MB (r16/r17) -> the harness's per-iteration
// workspace POISON costs ~34us. Fix: xp1 is written IN PLACE over dead xp0
// cells (out cols 256..511): xp0 row r is dead after producer step r
// (flagsP-ordered); fuser overwrites it with xp1 row r; consumer reads it
// (same address) and then overwrites with h1 row r at the end of its step r
// (same thread, program order - r8-r13-validated alias discipline).
// Ordering chain: proj0 -> projf -> producer -> flagsP -> fuser -> flagsF
// -> consumer. Workspace: 1.4 KB of flags only.
// ---------------------------------------------------------------------------
template<bool PUB, bool WAIT>
__device__ __forceinline__ void scan_core(
    int grp, ushort_t (*hb)[4096],
    const float* xp, int xp_stride, int xp_col,
    float* hout, int out_col,
    const float* Wrec, const float* Wmask, const float* tau_raw,
    unsigned int* flag, const unsigned int* projf)
{
    const int tid  = threadIdx.x;
    const int lane = tid & 63;
    const int wv   = tid >> 6;     // 0..7
    const int quad = lane >> 4;
    const int l15  = lane & 15;
    const int n0   = wv * 32;
    const int bg   = grp * 8;

    bf16x8 Bf[2][8];
    #pragma unroll
    for (int tc = 0; tc < 2; ++tc)
        #pragma unroll
        for (int kk = 0; kk < 8; ++kk)
            Bf[tc][kk] = load_bfrag(Wrec, Wmask,
                (size_t)(n0 + tc * 16 + l15) * H_ + kk * 32 + quad * 8);

    float inv_tau[2], h_prev[2][2];
    float xp_c[2][2], xp_n[2][2], xp_nn[2][2];
    #pragma unroll
    for (int tc = 0; tc < 2; ++tc) {
        inv_tau[tc] = 1.0f / (logf(1.0f + __expf(tau_raw[n0 + tc * 16 + l15])) + 0.1f);
        #pragma unroll
        for (int reg = 0; reg < 2; ++reg) {
            h_prev[tc][reg] = 0.0f;
            xp_c[tc][reg] = xp_n[tc][reg] = xp_nn[tc][reg] = 0.0f;
        }
    }

    int woff[2][2];
    #pragma unroll
    for (int tc = 0; tc < 2; ++tc)
        #pragma unroll
        for (int reg = 0; reg < 2; ++reg)
            woff[tc][reg] = a_off(quad * 4 + reg, n0 + tc * 16 + l15);
    const int ab = ((l15 & 2) == 0) ? (lane * 8) : 0;

    if (!WAIT) {   // prologue loads for t=0,1 (WAIT loads at chunk tops)
        if (PUB && projf != nullptr) {    // xp0 window 0 (rows 0..7) ready?
            if (tid < 8) {
                for (;;) {
                    unsigned v = __hip_atomic_load(&projf[bg + tid],
                                                   __ATOMIC_ACQUIRE,
                                                   __HIP_MEMORY_SCOPE_AGENT);
                    if (v == MAGIC) break;
                    __builtin_amdgcn_s_sleep(2);
                }
            }
            __syncthreads();
        }
        #pragma unroll
        for (int tc = 0; tc < 2; ++tc)
            #pragma unroll
            for (int reg = 0; reg < 2; ++reg) {
                const int b = bg + quad * 2 + reg;
                const int c = n0 + tc * 16 + l15;
                xp_c[tc][reg] = xp[(size_t)(b * T_ + 0) * xp_stride + xp_col + c];
                xp_n[tc][reg] = xp[(size_t)(b * T_ + 1) * xp_stride + xp_col + c];
            }
    }

    for (int i = tid; i < 4096; i += 512)
        ((unsigned int*)&hb[0][0])[i] = 0u;   // zero both buffers (16 KB)
    __syncthreads();

    for (int t = 0; t < T_; ++t) {
        const int rb = t & 1;

        #pragma unroll
        for (int tc = 0; tc < 2; ++tc)
            #pragma unroll
            for (int kk = 0; kk < 8; ++kk)
                PIN_FRAG(Bf[tc][kk]);

        if (WAIT && (t & 7) == 0) {
            if (tid == 0) {
                const unsigned need = (unsigned)(t >> 3) + 1u;
                for (;;) {
                    unsigned d = __hip_atomic_load(flag, __ATOMIC_ACQUIRE,
                                                   __HIP_MEMORY_SCOPE_AGENT) - MAGIC;
                    if (d >= need && d <= 16u) break;
                    __builtin_amdgcn_s_sleep(2);
                }
            }
            __syncthreads();
            #pragma unroll
            for (int tc = 0; tc < 2; ++tc)
                #pragma unroll
                for (int reg = 0; reg < 2; ++reg) {
                    const int b = bg + quad * 2 + reg;
                    xp_c[tc][reg] = xp[(size_t)(b * T_ + t) * xp_stride + xp_col
                                       + n0 + tc * 16 + l15];
                }
        }

        // A fragments (h(t-1)): linear conflict-free b128; pad lanes broadcast
        bf16x8 Af[8];
        {
            const ushort_t* a0 = &hb[rb][0];
            #pragma unroll
            for (int kk = 0; kk < 8; ++kk)
                Af[kk] = *(const bf16x8*)(a0 + ab + kk * 512);
        }

        // prefetch
        if (WAIT) {
            if ((t & 7) != 7 && t + 1 < T_) {
                #pragma unroll
                for (int tc = 0; tc < 2; ++tc)
                    #pragma unroll
                    for (int reg = 0; reg < 2; ++reg) {
                        const int b = bg + quad * 2 + reg;
                        xp_n[tc][reg] = xp[(size_t)(b * T_ + t + 1) * xp_stride
                                           + xp_col + n0 + tc * 16 + l15];
                    }
            }
        } else if (t + 2 < T_) {
            if (PUB && projf != nullptr) {
                // entering a new proj window? schedule {8,24,32,32,32}
                const int tp2 = t + 2;
                const int w = (tp2 == 8) ? 1 : (tp2 == 32) ? 2
                            : (tp2 == 64) ? 3 : (tp2 == 96) ? 4 : -1;
                if (w >= 0) {
                    if (tid < 8) {
                        for (;;) {
                            unsigned v = __hip_atomic_load(&projf[w * 64 + bg + tid],
                                                           __ATOMIC_ACQUIRE,
                                                           __HIP_MEMORY_SCOPE_AGENT);
                            if (v == MAGIC) break;
                            __builtin_amdgcn_s_sleep(2);
                        }
                    }
                    __syncthreads();
                }
            }
            #pragma unroll
            for (int tc = 0; tc < 2; ++tc)
                #pragma unroll
                for (int reg = 0; reg < 2; ++reg) {
                    const int b = bg + quad * 2 + reg;
                    xp_nn[tc][reg] = xp[(size_t)(b * T_ + t + 2) * xp_stride
                                        + xp_col + n0 + tc * 16 + l15];
                }
        }

        f32x4 acc[2] = {{0.f,0.f,0.f,0.f},{0.f,0.f,0.f,0.f}};
        #pragma unroll
        for (int kk = 0; kk < 8; ++kk)
            #pragma unroll
            for (int tc = 0; tc < 2; ++tc)
                acc[tc] = __builtin_amdgcn_mfma_f32_16x16x32_bf16(
                    Af[kk], Bf[tc][kk], acc[tc], 0, 0, 0);

        #pragma unroll
        for (int tc = 0; tc < 2; ++tc) {
            const int c = n0 + tc * 16 + l15;
            #pragma unroll
            for (int reg = 0; reg < 2; ++reg) {
                const int b = bg + quad * 2 + reg;
                const float pre = xp_c[tc][reg] + acc[tc][reg];
                const float hn  = h_prev[tc][reg]
                                + (fast_tanh(pre) - h_prev[tc][reg]) * inv_tau[tc];
                h_prev[tc][reg] = hn;
                hb[rb ^ 1][woff[tc][reg]] = f2bf(hn);
                if (PUB)   // agent-scope: cross-XCD visible once retired
                    __hip_atomic_store(&hout[(size_t)(b * T_ + t) * OW_ + out_col + c],
                                       hn, __ATOMIC_RELAXED, __HIP_MEMORY_SCOPE_AGENT);
                else
                    hout[(size_t)(b * T_ + t) * OW_ + out_col + c] = hn;
            }
        }
        if (WAIT) {
            if ((t & 7) != 7) {
                #pragma unroll
                for (int tc = 0; tc < 2; ++tc)
                    #pragma unroll
                    for (int reg = 0; reg < 2; ++reg)
                        xp_c[tc][reg] = xp_n[tc][reg];
            }
        } else {
            #pragma unroll
            for (int tc = 0; tc < 2; ++tc)
                #pragma unroll
                for (int reg = 0; reg < 2; ++reg) {
                    xp_c[tc][reg] = xp_n[tc][reg];
                    xp_n[tc][reg] = xp_nn[tc][reg];
                }
        }

        if (PUB && (t & 7) == 7) {
            __syncthreads();   // drains vmcnt -> h0 rows <= t retired
            if (tid == 0)
                __hip_atomic_store(flag, MAGIC + (unsigned)((t >> 3) + 1),
                                   __ATOMIC_RELEASE, __HIP_MEMORY_SCOPE_AGENT);
        } else if (t + 1 < T_) {
            LGKM_BARRIER();
        }
    }
}

// ---------------------------------------------------------------------------
// fuser_core (r18): per 8-step chunk c: wait producer flagsP >= c, stage the
// 64 h0 rows (8 batches x 8 t, out cols 0..255) row-major, compute
// xp1 = h0 @ Wi1^T + b1 as a batched GEMM, and store it IN PLACE over the
// dead xp0 cells (out cols 256..511, agent-scope), release flagsF = c.
// Values bit-identical to the r8-r17 fuse (same f2bf(h0) @ bf16(Wi1)).
// ---------------------------------------------------------------------------
__device__ __forceinline__ void fuser_core(
    int grp, ushort_t (*As)[LP],
    float* __restrict__ out,                 // h0 in cols 0..255; xp1 -> 256..511
    const float* __restrict__ Wi1, const float* __restrict__ b1v,
    const unsigned int* flagP, unsigned int* flagF)
{
    const int tid  = threadIdx.x;
    const int lane = tid & 63;
    const int wv   = tid >> 6;
    const int quad = lane >> 4;
    const int l15  = lane & 15;
    const int n0   = wv * 32;
    const int bg   = grp * 8;

    bf16x8 Bf[2][8];
    float  bj[2];
    #pragma unroll
    for (int tc = 0; tc < 2; ++tc) {
        const int c = n0 + tc * 16 + l15;
        bj[tc] = b1v[c];
        #pragma unroll
        for (int kk = 0; kk < 8; ++kk)
            Bf[tc][kk] = load_bfrag(Wi1, nullptr,
                                    (size_t)c * H_ + kk * 32 + quad * 8);
    }

    const int srow = tid >> 3;        // 0..63: chunk row
    const int sseg = tid & 7;         // 32-col segment
    const int sb   = bg + (srow >> 3);

    for (int c = 1; c <= 16; ++c) {
        if (tid == 0) {
            for (;;) {
                unsigned d = __hip_atomic_load(flagP, __ATOMIC_ACQUIRE,
                                               __HIP_MEMORY_SCOPE_AGENT) - MAGIC;
                if (d >= (unsigned)c && d <= 16u) break;
                __builtin_amdgcn_s_sleep(2);
            }
        }
        __syncthreads();
        const int t0 = (c - 1) * 8;

        {   // stage 64 rows of h0 (f32 -> bf16), row-major [64][LP]
            const float* srcp = out
                + (size_t)(sb * T_ + t0 + (srow & 7)) * OW_ + sseg * 32;
            union { uint4 q[4]; ushort_t u[32]; } pk;
            #pragma unroll
            for (int h = 0; h < 4; ++h) {
                float4 f0 = *(const float4*)(srcp + h * 8);
                float4 f1 = *(const float4*)(srcp + h * 8 + 4);
                pk.u[h*8+0] = f2bf(f0.x); pk.u[h*8+1] = f2bf(f0.y);
                pk.u[h*8+2] = f2bf(f0.z); pk.u[h*8+3] = f2bf(f0.w);
                pk.u[h*8+4] = f2bf(f1.x); pk.u[h*8+5] = f2bf(f1.y);
                pk.u[h*8+6] = f2bf(f1.z); pk.u[h*8+7] = f2bf(f1.w);
            }
            #pragma unroll
            for (int h = 0; h < 4; ++h)
                *(uint4*)&As[srow][sseg * 32 + h * 8] = pk.q[h];
        }
        __syncthreads();

        #pragma unroll
        for (int rt = 0; rt < 4; ++rt) {
            bf16x8 Af[8];
            #pragma unroll
            for (int kk = 0; kk < 8; ++kk)
                Af[kk] = *(const bf16x8*)&As[rt * 16 + l15][kk * 32 + quad * 8];

            f32x4 acc[2] = {{bj[0],bj[0],bj[0],bj[0]},
                            {bj[1],bj[1],bj[1],bj[1]}};
            #pragma unroll
            for (int kk = 0; kk < 8; ++kk)
                #pragma unroll
                for (int tc = 0; tc < 2; ++tc)
                    acc[tc] = __builtin_amdgcn_mfma_f32_16x16x32_bf16(
                        Af[kk], Bf[tc][kk], acc[tc], 0, 0, 0);

            #pragma unroll
            for (int tc = 0; tc < 2; ++tc) {
                const int cc = n0 + tc * 16 + l15;
                #pragma unroll
                for (int reg = 0; reg < 4; ++reg) {
                    const int r  = rt * 16 + quad * 4 + reg;
                    const int b  = bg + (r >> 3);
                    const int tt = t0 + (r & 7);
                    // in-place over dead xp0 (cols 256..511), agent-scope
                    __hip_atomic_store(&out[(size_t)(b * T_ + tt) * OW_ + H_ + cc],
                                       acc[tc][reg],
                                       __ATOMIC_RELAXED, __HIP_MEMORY_SCOPE_AGENT);
                }
            }
        }
        __syncthreads();   // drains vmcnt (xp1 retired) + protects As reuse
        if (tid == 0)
            __hip_atomic_store(flagF, MAGIC + (unsigned)c,
                               __ATOMIC_RELEASE, __HIP_MEMORY_SCOPE_AGENT);
    }
}

// ---------------------------------------------------------------------------
// proj body: dst[r0+r][dst_col+n] = bias[n] + src[row(r)] @ Wi^T, nrows<=32.
// done != nullptr: agent-scope stores + per-block done flag (MAGIC, release).
// ---------------------------------------------------------------------------
__device__ __forceinline__ void proj_body(
    ushort_t (*As)[LP], int r0, int nrows,
    const float* __restrict__ src, int src_stride, int src_col,
    const int* __restrict__ tok,
    const float* __restrict__ Wi, const float* __restrict__ bias,
    float* __restrict__ dst, int dst_stride, int dst_col,
    unsigned int* done, int done_idx)
{
    const int tid  = threadIdx.x;
    const int lane = tid & 63;
    const int wv   = tid >> 6;
    const int quad = lane >> 4;
    const int l15  = lane & 15;
    const int n0   = wv * 32;

    bf16x8 Bf[2][8];
    float  bj[2];
    #pragma unroll
    for (int tc = 0; tc < 2; ++tc) {
        const int n = n0 + tc * 16 + l15;
        bj[tc] = bias[n];
        #pragma unroll
        for (int kk = 0; kk < 8; ++kk)
            Bf[tc][kk] = load_bfrag(Wi, nullptr, (size_t)n * H_ + kk * 32 + quad * 8);
    }

    {
        const int row = tid >> 4;
        const int seg = tid & 15;
        if (row < nrows) {
            const size_t sb = (tok ? (size_t)tok[r0 + row] : (size_t)(r0 + row))
                              * src_stride + src_col + seg * 16;
            union { uint4 q[2]; ushort_t u[16]; } p;
            #pragma unroll
            for (int h = 0; h < 2; ++h) {
                float4 f0 = *(const float4*)(src + sb + h * 8);
                float4 f1 = *(const float4*)(src + sb + h * 8 + 4);
                p.u[h*8+0] = f2bf(f0.x); p.u[h*8+1] = f2bf(f0.y);
                p.u[h*8+2] = f2bf(f0.z); p.u[h*8+3] = f2bf(f0.w);
                p.u[h*8+4] = f2bf(f1.x); p.u[h*8+5] = f2bf(f1.y);
                p.u[h*8+6] = f2bf(f1.z); p.u[h*8+7] = f2bf(f1.w);
            }
            *(uint4*)&As[row][seg * 16]     = p.q[0];
            *(uint4*)&As[row][seg * 16 + 8] = p.q[1];
        }
    }
    __syncthreads();

    #pragma unroll
    for (int rt = 0; rt < 2; ++rt) {
        if (rt * 16 >= nrows) break;   // garbage tiles skipped entirely
        bf16x8 Af[8];
        #pragma unroll
        for (int kk = 0; kk < 8; ++kk)
            Af[kk] = *(const bf16x8*)&As[rt * 16 + l15][kk * 32 + quad * 8];

        f32x4 acc[2] = {{bj[0],bj[0],bj[0],bj[0]}, {bj[1],bj[1],bj[1],bj[1]}};
        #pragma unroll
        for (int kk = 0; kk < 8; ++kk)
            #pragma unroll
            for (int tc = 0; tc < 2; ++tc)
                acc[tc] = __builtin_amdgcn_mfma_f32_16x16x32_bf16(
                    Af[kk], Bf[tc][kk], acc[tc], 0, 0, 0);

        #pragma unroll
        for (int tc = 0; tc < 2; ++tc) {
            const int c = n0 + tc * 16 + l15;
            #pragma unroll
            for (int reg = 0; reg < 4; ++reg) {
                const int rl = rt * 16 + quad * 4 + reg;
                if (rl < nrows) {
                    const int r = r0 + rl;
                    if (done)
                        __hip_atomic_store(&dst[(size_t)r * dst_stride + dst_col + c],
                                           acc[tc][reg],
                                           __ATOMIC_RELAXED, __HIP_MEMORY_SCOPE_AGENT);
                    else
                        dst[(size_t)r * dst_stride + dst_col + c] = acc[tc][reg];
                }
            }
        }
    }

    if (done) {
        __syncthreads();   // drains vmcnt -> all xp0 stores of this block retired
        if (tid == 0)
            __hip_atomic_store(&done[done_idx], MAGIC,
                               __ATOMIC_RELEASE, __HIP_MEMORY_SCOPE_AGENT);
    }
}

// ---------------------------------------------------------------------------
// Single dispatch, 4 roles: 0..7 producers (rec0, publishes h0 chunks),
// 8..15 consumers (rec1, reads xp1 from dead-xp0 cells), 16..23 fusers
// (xp1 = h0 @ Wi1^T + b1 in place), 24..343 proj0 blocks (windows
// {8,24,32,32,32} rows/batch; w=0 first for a short producer prologue stall).
// ---------------------------------------------------------------------------
__global__ __launch_bounds__(512, 1)
void ltc_all(const int* __restrict__ tokens, const float* __restrict__ emb,
             const float* __restrict__ Wi0, const float* __restrict__ b0v,
             const float* __restrict__ Wr0, const float* __restrict__ m0,
             const float* __restrict__ t0v,
             const float* __restrict__ Wi1, const float* __restrict__ b1v,
             const float* __restrict__ Wr1, const float* __restrict__ m1,
             const float* __restrict__ t1v,
             float* out,
             unsigned int* flagsP, unsigned int* flagsF, unsigned int* projf)
{
    __shared__ __align__(16) ushort_t smem[64][LP];   // 33792 B, role-shared
    if (blockIdx.x < 8)
        scan_core<true, false>(blockIdx.x, (ushort_t(*)[4096])&smem[0][0],
                               out, OW_, H_,     // xp0 in out cols 256..511
                               out, 0,           // h0 -> cols 0..255 (agent)
                               Wr0, m0, t0v, flagsP + blockIdx.x, projf);
    else if (blockIdx.x < 16)
        scan_core<false, true>(blockIdx.x - 8, (ushort_t(*)[4096])&smem[0][0],
                               out, OW_, H_,     // xp1 from dead-xp0 cells
                               out, H_,          // h1 -> cols 256..511
                               Wr1, m1, t1v, flagsF + (blockIdx.x - 8), nullptr);
    else if (blockIdx.x < 24)
        fuser_core(blockIdx.x - 16, smem, out, Wi1, b1v,
                   flagsP + (blockIdx.x - 16), flagsF + (blockIdx.x - 16));
    else {
        const int p = blockIdx.x - 24;
        const int w = p >> 6, b = p & 63;
        const int r0 = b * T_ + (w == 0 ? 0 : (w == 1 ? 8 : 32 * (w - 1)));
        const int nr = (w == 0 ? 8 : (w == 1 ? 24 : 32));
        proj_body((ushort_t(*)[LP])smem, r0, nr, emb, E_, 0, tokens,
                  Wi0, b0v, out, OW_, H_, projf, p);
    }
}

// ---------------------------------------------------------------------------
// Fallback path (ws too small): sequential proj + standalone scans (proven).
// ---------------------------------------------------------------------------
__global__ __launch_bounds__(512, 1)
void ltc_single(const float* xp, int xp_stride, int xp_col,
                float* hout, int out_col,
                const float* __restrict__ Wr, const float* __restrict__ mk,
                const float* __restrict__ tu)
{
    __shared__ __align__(16) ushort_t hb[2][4096];
    scan_core<false, false>(blockIdx.x, hb, xp, xp_stride, xp_col,
                            hout, out_col, Wr, mk, tu, nullptr, nullptr);
}

__global__ __launch_bounds__(512, 2)
void proj_mfma(const float* __restrict__ src, int src_stride, int src_col,
               const int* __restrict__ tok,
               const float* __restrict__ Wi,
               const float* __restrict__ bias,
               float* __restrict__ dst, int dst_stride, int dst_col)
{
    __shared__ __align__(16) ushort_t As[32][LP];
    proj_body(As, blockIdx.x * 32, 32, src, src_stride, src_col, tok, Wi, bias,
              dst, dst_stride, dst_col, nullptr, 0);
}

extern "C" void kernel_launch(void* const* d_in, const int* in_sizes, int n_in,
                              void* d_out, int out_size, void* d_ws, size_t ws_size,
                              hipStream_t stream)
{
    const int*   tokens = (const int*)d_in[0];
    const float* emb    = (const float*)d_in[1];
    const float* W_in0  = (const float*)d_in[2];
    const float* W_rec0 = (const float*)d_in[3];
    const float* b0     = (const float*)d_in[4];
    const float* tau0   = (const float*)d_in[5];
    const float* mask0  = (const float*)d_in[6];
    const float* W_in1  = (const float*)d_in[7];
    const float* W_rec1 = (const float*)d_in[8];
    const float* b1     = (const float*)d_in[9];
    const float* tau1   = (const float*)d_in[10];
    const float* mask1  = (const float*)d_in[11];
    float* out = (float*)d_out;    // [8192, 512] f32
    (void)in_sizes; (void)n_in; (void)out_size;

    // ws: [flagsP (64B) | flagsF (64B) | projf (320*4B)] -- 1.4 KB total.
    const size_t need = 64 + 64 + 320 * sizeof(unsigned int);

    if (ws_size >= need) {
        // all flags arrive poisoned (0xAA..) each launch -> not-ready; the
        // window checks (==MAGIC / MAGIC+c in [1,16]) treat poison as unset.
        unsigned int* flagsP = (unsigned int*)d_ws;
        unsigned int* flagsF = (unsigned int*)((char*)d_ws + 64);
        unsigned int* projf  = (unsigned int*)((char*)d_ws + 128);
        ltc_all<<<dim3(344), dim3(512), 0, stream>>>(
            tokens, emb, W_in0, b0, W_rec0, mask0, tau0,
            W_in1, b1, W_rec1, mask1, tau1, out, flagsP, flagsF, projf);
    } else {
        proj_mfma<<<dim3(256), dim3(512), 0, stream>>>(
            emb, E_, 0, tokens, W_in0, b0, out, OW_, H_);
        ltc_single<<<dim3(8), dim3(512), 0, stream>>>(
            out, OW_, H_, out, 0, W_rec0, mask0, tau0);
        proj_mfma<<<dim3(256), dim3(512), 0, stream>>>(
            out, OW_, 0, nullptr, W_in1, b1, out, OW_, H_);
        ltc_single<<<dim3(8), dim3(512), 0, stream>>>(
            out, OW_, H_, out, H_, W_rec1, mask1, tau1);
    }
}

// Round 11
// 234.847 us; speedup vs baseline: 1.0092x; 1.0092x over previous
//
#include <hip/hip_runtime.h>
#include <hip/hip_bf16.h>

#define B_ 64
#define T_ 128
#define E_ 256
#define H_ 256
#define OW_ 512   // output row width = 2*H (elements)
#define LP 264    // LDS bf16 row pitch for row-major staging tiles (elements)
#define MAGIC 0x5AD00000u

typedef unsigned short ushort_t;
typedef __attribute__((ext_vector_type(8))) short bf16x8;   // 8 bf16 = 4 VGPRs
typedef __attribute__((ext_vector_type(4))) float f32x4;    // 4 f32 acc

// Workgroup barrier WITHOUT the compiler's vmcnt(0) drain (validated r7/r8).
#define LGKM_BARRIER() asm volatile("s_waitcnt lgkmcnt(0)\n\ts_barrier" ::: "memory")
// Keep weight fragments loop-carried (r12).
#define PIN_FRAG(x) asm volatile("" : "+v"(x))

__device__ __forceinline__ ushort_t f2bf(float f) {
    unsigned int x = __float_as_uint(f);
    unsigned int r = x + 0x7FFFu + ((x >> 16) & 1u);
    return (ushort_t)(r >> 16);
}
__device__ __forceinline__ float fast_tanh(float x) {
    float e = __expf(2.0f * x);
    return 1.0f - 2.0f * __builtin_amdgcn_rcpf(e + 1.0f);
}
__device__ __forceinline__ bf16x8 load_bfrag(const float* W, const float* M,
                                             size_t base) {
    float4 a = *(const float4*)(W + base);
    float4 b = *(const float4*)(W + base + 4);
    if (M) {
        float4 ma = *(const float4*)(M + base);
        float4 mb = *(const float4*)(M + base + 4);
        a.x *= ma.x; a.y *= ma.y; a.z *= ma.z; a.w *= ma.w;
        b.x *= mb.x; b.y *= mb.y; b.z *= mb.z; b.w *= mb.w;
    }
    union { bf16x8 v; ushort_t u[8]; } r;
    r.u[0] = f2bf(a.x); r.u[1] = f2bf(a.y); r.u[2] = f2bf(a.z); r.u[3] = f2bf(a.w);
    r.u[4] = f2bf(b.x); r.u[5] = f2bf(b.y); r.u[6] = f2bf(b.z); r.u[7] = f2bf(b.w);
    return r.v;
}

// Fragment-major LDS A-layout for hb (r9-verified): element (r,k) at
//   off = (k>>5)*512 + ((k>>3)&3)*128 + r*8 + (k&7)
// Reader lane L reads frag kk as b128 at element L*8 + kk*512 (linear,
// conflict-free). Pad-row lanes ((l15&2)!=0; C rows discarded) broadcast.
__device__ __forceinline__ int a_off(int r, int k) {
    return ((k >> 5) << 9) + (((k >> 3) & 3) << 7) + (r << 3) + (k & 7);
}

// ---------------------------------------------------------------------------
// r19 = r18 pipeline (producer -> fuser -> consumer, proj0 in-dispatch,
// xp1 in place over dead xp0, flags-only workspace) + ADDRESS STRENGTH
// REDUCTION in the serial scan loop. r18 evidence: scan-CU VALU load is a
// co-dominant per-step term; each thread recomputed 8 global addresses per
// step with 64-bit muls ((b*T_+t)*stride+c). All of them advance by a
// CONSTANT per step -> running pointers pout[2][2]/pxp[2][2] (statically
// indexed after unroll, live in VGPRs), incremented once per step.
// Ordering chain unchanged: proj0 -> projf -> producer -> flagsP -> fuser
// -> flagsF -> consumer. Alias discipline unchanged (r8-r18-validated).
// ---------------------------------------------------------------------------
template<bool PUB, bool WAIT>
__device__ __forceinline__ void scan_core(
    int grp, ushort_t (*hb)[4096],
    const float* xp, int xp_stride, int xp_col,
    float* hout, int out_col,
    const float* Wrec, const float* Wmask, const float* tau_raw,
    unsigned int* flag, const unsigned int* projf)
{
    const int tid  = threadIdx.x;
    const int lane = tid & 63;
    const int wv   = tid >> 6;     // 0..7
    const int quad = lane >> 4;
    const int l15  = lane & 15;
    const int n0   = wv * 32;
    const int bg   = grp * 8;

    bf16x8 Bf[2][8];
    #pragma unroll
    for (int tc = 0; tc < 2; ++tc)
        #pragma unroll
        for (int kk = 0; kk < 8; ++kk)
            Bf[tc][kk] = load_bfrag(Wrec, Wmask,
                (size_t)(n0 + tc * 16 + l15) * H_ + kk * 32 + quad * 8);

    float inv_tau[2], h_prev[2][2];
    float xp_c[2][2], xp_n[2][2], xp_nn[2][2];
    #pragma unroll
    for (int tc = 0; tc < 2; ++tc) {
        inv_tau[tc] = 1.0f / (logf(1.0f + __expf(tau_raw[n0 + tc * 16 + l15])) + 0.1f);
        #pragma unroll
        for (int reg = 0; reg < 2; ++reg) {
            h_prev[tc][reg] = 0.0f;
            xp_c[tc][reg] = xp_n[tc][reg] = xp_nn[tc][reg] = 0.0f;
        }
    }

    int woff[2][2];
    #pragma unroll
    for (int tc = 0; tc < 2; ++tc)
        #pragma unroll
        for (int reg = 0; reg < 2; ++reg)
            woff[tc][reg] = a_off(quad * 4 + reg, n0 + tc * 16 + l15);
    const int ab = ((l15 & 2) == 0) ? (lane * 8) : 0;

    // r19: running pointers. pxp -> row t+2 (producer) / row t (consumer);
    // pout -> row t. Advance by a constant each step; deref only when guarded.
    const float* pxp[2][2];
    float*       pout[2][2];
    #pragma unroll
    for (int tc = 0; tc < 2; ++tc)
        #pragma unroll
        for (int reg = 0; reg < 2; ++reg) {
            const int b = bg + quad * 2 + reg;
            const int c = n0 + tc * 16 + l15;
            pxp[tc][reg]  = xp + (size_t)(b * T_ + (WAIT ? 0 : 2)) * xp_stride
                              + xp_col + c;
            pout[tc][reg] = hout + (size_t)(b * T_) * OW_ + out_col + c;
        }

    if (!WAIT) {   // prologue loads for t=0,1 (WAIT loads at chunk tops)
        if (PUB && projf != nullptr) {    // xp0 window 0 (rows 0..7) ready?
            if (tid < 8) {
                for (;;) {
                    unsigned v = __hip_atomic_load(&projf[bg + tid],
                                                   __ATOMIC_ACQUIRE,
                                                   __HIP_MEMORY_SCOPE_AGENT);
                    if (v == MAGIC) break;
                    __builtin_amdgcn_s_sleep(2);
                }
            }
            __syncthreads();
        }
        #pragma unroll
        for (int tc = 0; tc < 2; ++tc)
            #pragma unroll
            for (int reg = 0; reg < 2; ++reg) {
                const int b = bg + quad * 2 + reg;
                const int c = n0 + tc * 16 + l15;
                xp_c[tc][reg] = xp[(size_t)(b * T_ + 0) * xp_stride + xp_col + c];
                xp_n[tc][reg] = xp[(size_t)(b * T_ + 1) * xp_stride + xp_col + c];
            }
    }

    for (int i = tid; i < 4096; i += 512)
        ((unsigned int*)&hb[0][0])[i] = 0u;   // zero both buffers (16 KB)
    __syncthreads();

    for (int t = 0; t < T_; ++t) {
        const int rb = t & 1;

        #pragma unroll
        for (int tc = 0; tc < 2; ++tc)
            #pragma unroll
            for (int kk = 0; kk < 8; ++kk)
                PIN_FRAG(Bf[tc][kk]);

        if (WAIT && (t & 7) == 0) {
            if (tid == 0) {
                const unsigned need = (unsigned)(t >> 3) + 1u;
                for (;;) {
                    unsigned d = __hip_atomic_load(flag, __ATOMIC_ACQUIRE,
                                                   __HIP_MEMORY_SCOPE_AGENT) - MAGIC;
                    if (d >= need && d <= 16u) break;
                    __builtin_amdgcn_s_sleep(2);
                }
            }
            __syncthreads();
            #pragma unroll
            for (int tc = 0; tc < 2; ++tc)
                #pragma unroll
                for (int reg = 0; reg < 2; ++reg)
                    xp_c[tc][reg] = *pxp[tc][reg];          // row t
        }

        // A fragments (h(t-1)): linear conflict-free b128; pad lanes broadcast
        bf16x8 Af[8];
        {
            const ushort_t* a0 = &hb[rb][0];
            #pragma unroll
            for (int kk = 0; kk < 8; ++kk)
                Af[kk] = *(const bf16x8*)(a0 + ab + kk * 512);
        }

        // prefetch
        if (WAIT) {
            if ((t & 7) != 7 && t + 1 < T_) {
                #pragma unroll
                for (int tc = 0; tc < 2; ++tc)
                    #pragma unroll
                    for (int reg = 0; reg < 2; ++reg)
                        xp_n[tc][reg] = *(pxp[tc][reg] + xp_stride);   // row t+1
            }
        } else if (t + 2 < T_) {
            if (PUB && projf != nullptr) {
                // entering a new proj window? schedule {8,24,32,32,32}
                const int tp2 = t + 2;
                const int w = (tp2 == 8) ? 1 : (tp2 == 32) ? 2
                            : (tp2 == 64) ? 3 : (tp2 == 96) ? 4 : -1;
                if (w >= 0) {
                    if (tid < 8) {
                        for (;;) {
                            unsigned v = __hip_atomic_load(&projf[w * 64 + bg + tid],
                                                           __ATOMIC_ACQUIRE,
                                                           __HIP_MEMORY_SCOPE_AGENT);
                            if (v == MAGIC) break;
                            __builtin_amdgcn_s_sleep(2);
                        }
                    }
                    __syncthreads();
                }
            }
            #pragma unroll
            for (int tc = 0; tc < 2; ++tc)
                #pragma unroll
                for (int reg = 0; reg < 2; ++reg)
                    xp_nn[tc][reg] = *pxp[tc][reg];         // row t+2
        }

        f32x4 acc[2] = {{0.f,0.f,0.f,0.f},{0.f,0.f,0.f,0.f}};
        #pragma unroll
        for (int kk = 0; kk < 8; ++kk)
            #pragma unroll
            for (int tc = 0; tc < 2; ++tc)
                acc[tc] = __builtin_amdgcn_mfma_f32_16x16x32_bf16(
                    Af[kk], Bf[tc][kk], acc[tc], 0, 0, 0);

        #pragma unroll
        for (int tc = 0; tc < 2; ++tc) {
            #pragma unroll
            for (int reg = 0; reg < 2; ++reg) {
                const float pre = xp_c[tc][reg] + acc[tc][reg];
                const float hn  = h_prev[tc][reg]
                                + (fast_tanh(pre) - h_prev[tc][reg]) * inv_tau[tc];
                h_prev[tc][reg] = hn;
                hb[rb ^ 1][woff[tc][reg]] = f2bf(hn);
                if (PUB)   // agent-scope: cross-XCD visible once retired
                    __hip_atomic_store(pout[tc][reg], hn,
                                       __ATOMIC_RELAXED, __HIP_MEMORY_SCOPE_AGENT);
                else
                    *pout[tc][reg] = hn;
            }
        }
        if (WAIT) {
            if ((t & 7) != 7) {
                #pragma unroll
                for (int tc = 0; tc < 2; ++tc)
                    #pragma unroll
                    for (int reg = 0; reg < 2; ++reg)
                        xp_c[tc][reg] = xp_n[tc][reg];
            }
        } else {
            #pragma unroll
            for (int tc = 0; tc < 2; ++tc)
                #pragma unroll
                for (int reg = 0; reg < 2; ++reg) {
                    xp_c[tc][reg] = xp_n[tc][reg];
                    xp_n[tc][reg] = xp_nn[tc][reg];
                }
        }

        // advance running pointers (constant strides; no deref past range)
        #pragma unroll
        for (int tc = 0; tc < 2; ++tc)
            #pragma unroll
            for (int reg = 0; reg < 2; ++reg) {
                pxp[tc][reg]  += xp_stride;
                pout[tc][reg] += OW_;
            }

        if (PUB && (t & 7) == 7) {
            __syncthreads();   // drains vmcnt -> h0 rows <= t retired
            if (tid == 0)
                __hip_atomic_store(flag, MAGIC + (unsigned)((t >> 3) + 1),
                                   __ATOMIC_RELEASE, __HIP_MEMORY_SCOPE_AGENT);
        } else if (t + 1 < T_) {
            LGKM_BARRIER();
        }
    }
}

// ---------------------------------------------------------------------------
// fuser_core (r18): per 8-step chunk c: wait producer flagsP >= c, stage the
// 64 h0 rows (8 batches x 8 t, out cols 0..255) row-major, compute
// xp1 = h0 @ Wi1^T + b1 as a batched GEMM, and store it IN PLACE over the
// dead xp0 cells (out cols 256..511, agent-scope), release flagsF = c.
// Values bit-identical to the r8-r18 fuse (same f2bf(h0) @ bf16(Wi1)).
// ---------------------------------------------------------------------------
__device__ __forceinline__ void fuser_core(
    int grp, ushort_t (*As)[LP],
    float* __restrict__ out,                 // h0 in cols 0..255; xp1 -> 256..511
    const float* __restrict__ Wi1, const float* __restrict__ b1v,
    const unsigned int* flagP, unsigned int* flagF)
{
    const int tid  = threadIdx.x;
    const int lane = tid & 63;
    const int wv   = tid >> 6;
    const int quad = lane >> 4;
    const int l15  = lane & 15;
    const int n0   = wv * 32;
    const int bg   = grp * 8;

    bf16x8 Bf[2][8];
    float  bj[2];
    #pragma unroll
    for (int tc = 0; tc < 2; ++tc) {
        const int c = n0 + tc * 16 + l15;
        bj[tc] = b1v[c];
        #pragma unroll
        for (int kk = 0; kk < 8; ++kk)
            Bf[tc][kk] = load_bfrag(Wi1, nullptr,
                                    (size_t)c * H_ + kk * 32 + quad * 8);
    }

    const int srow = tid >> 3;        // 0..63: chunk row
    const int sseg = tid & 7;         // 32-col segment
    const int sb   = bg + (srow >> 3);

    for (int c = 1; c <= 16; ++c) {
        if (tid == 0) {
            for (;;) {
                unsigned d = __hip_atomic_load(flagP, __ATOMIC_ACQUIRE,
                                               __HIP_MEMORY_SCOPE_AGENT) - MAGIC;
                if (d >= (unsigned)c && d <= 16u) break;
                __builtin_amdgcn_s_sleep(2);
            }
        }
        __syncthreads();
        const int t0 = (c - 1) * 8;

        {   // stage 64 rows of h0 (f32 -> bf16), row-major [64][LP]
            const float* srcp = out
                + (size_t)(sb * T_ + t0 + (srow & 7)) * OW_ + sseg * 32;
            union { uint4 q[4]; ushort_t u[32]; } pk;
            #pragma unroll
            for (int h = 0; h < 4; ++h) {
                float4 f0 = *(const float4*)(srcp + h * 8);
                float4 f1 = *(const float4*)(srcp + h * 8 + 4);
                pk.u[h*8+0] = f2bf(f0.x); pk.u[h*8+1] = f2bf(f0.y);
                pk.u[h*8+2] = f2bf(f0.z); pk.u[h*8+3] = f2bf(f0.w);
                pk.u[h*8+4] = f2bf(f1.x); pk.u[h*8+5] = f2bf(f1.y);
                pk.u[h*8+6] = f2bf(f1.z); pk.u[h*8+7] = f2bf(f1.w);
            }
            #pragma unroll
            for (int h = 0; h < 4; ++h)
                *(uint4*)&As[srow][sseg * 32 + h * 8] = pk.q[h];
        }
        __syncthreads();

        #pragma unroll
        for (int rt = 0; rt < 4; ++rt) {
            bf16x8 Af[8];
            #pragma unroll
            for (int kk = 0; kk < 8; ++kk)
                Af[kk] = *(const bf16x8*)&As[rt * 16 + l15][kk * 32 + quad * 8];

            f32x4 acc[2] = {{bj[0],bj[0],bj[0],bj[0]},
                            {bj[1],bj[1],bj[1],bj[1]}};
            #pragma unroll
            for (int kk = 0; kk < 8; ++kk)
                #pragma unroll
                for (int tc = 0; tc < 2; ++tc)
                    acc[tc] = __builtin_amdgcn_mfma_f32_16x16x32_bf16(
                        Af[kk], Bf[tc][kk], acc[tc], 0, 0, 0);

            #pragma unroll
            for (int tc = 0; tc < 2; ++tc) {
                const int cc = n0 + tc * 16 + l15;
                #pragma unroll
                for (int reg = 0; reg < 4; ++reg) {
                    const int r  = rt * 16 + quad * 4 + reg;
                    const int b  = bg + (r >> 3);
                    const int tt = t0 + (r & 7);
                    // in-place over dead xp0 (cols 256..511), agent-scope
                    __hip_atomic_store(&out[(size_t)(b * T_ + tt) * OW_ + H_ + cc],
                                       acc[tc][reg],
                                       __ATOMIC_RELAXED, __HIP_MEMORY_SCOPE_AGENT);
                }
            }
        }
        __syncthreads();   // drains vmcnt (xp1 retired) + protects As reuse
        if (tid == 0)
            __hip_atomic_store(flagF, MAGIC + (unsigned)c,
                               __ATOMIC_RELEASE, __HIP_MEMORY_SCOPE_AGENT);
    }
}

// ---------------------------------------------------------------------------
// proj body: dst[r0+r][dst_col+n] = bias[n] + src[row(r)] @ Wi^T, nrows<=32.
// done != nullptr: agent-scope stores + per-block done flag (MAGIC, release).
// ---------------------------------------------------------------------------
__device__ __forceinline__ void proj_body(
    ushort_t (*As)[LP], int r0, int nrows,
    const float* __restrict__ src, int src_stride, int src_col,
    const int* __restrict__ tok,
    const float* __restrict__ Wi, const float* __restrict__ bias,
    float* __restrict__ dst, int dst_stride, int dst_col,
    unsigned int* done, int done_idx)
{
    const int tid  = threadIdx.x;
    const int lane = tid & 63;
    const int wv   = tid >> 6;
    const int quad = lane >> 4;
    const int l15  = lane & 15;
    const int n0   = wv * 32;

    bf16x8 Bf[2][8];
    float  bj[2];
    #pragma unroll
    for (int tc = 0; tc < 2; ++tc) {
        const int n = n0 + tc * 16 + l15;
        bj[tc] = bias[n];
        #pragma unroll
        for (int kk = 0; kk < 8; ++kk)
            Bf[tc][kk] = load_bfrag(Wi, nullptr, (size_t)n * H_ + kk * 32 + quad * 8);
    }

    {
        const int row = tid >> 4;
        const int seg = tid & 15;
        if (row < nrows) {
            const size_t sb = (tok ? (size_t)tok[r0 + row] : (size_t)(r0 + row))
                              * src_stride + src_col + seg * 16;
            union { uint4 q[2]; ushort_t u[16]; } p;
            #pragma unroll
            for (int h = 0; h < 2; ++h) {
                float4 f0 = *(const float4*)(src + sb + h * 8);
                float4 f1 = *(const float4*)(src + sb + h * 8 + 4);
                p.u[h*8+0] = f2bf(f0.x); p.u[h*8+1] = f2bf(f0.y);
                p.u[h*8+2] = f2bf(f0.z); p.u[h*8+3] = f2bf(f0.w);
                p.u[h*8+4] = f2bf(f1.x); p.u[h*8+5] = f2bf(f1.y);
                p.u[h*8+6] = f2bf(f1.z); p.u[h*8+7] = f2bf(f1.w);
            }
            *(uint4*)&As[row][seg * 16]     = p.q[0];
            *(uint4*)&As[row][seg * 16 + 8] = p.q[1];
        }
    }
    __syncthreads();

    #pragma unroll
    for (int rt = 0; rt < 2; ++rt) {
        if (rt * 16 >= nrows) break;   // garbage tiles skipped entirely
        bf16x8 Af[8];
        #pragma unroll
        for (int kk = 0; kk < 8; ++kk)
            Af[kk] = *(const bf16x8*)&As[rt * 16 + l15][kk * 32 + quad * 8];

        f32x4 acc[2] = {{bj[0],bj[0],bj[0],bj[0]}, {bj[1],bj[1],bj[1],bj[1]}};
        #pragma unroll
        for (int kk = 0; kk < 8; ++kk)
            #pragma unroll
            for (int tc = 0; tc < 2; ++tc)
                acc[tc] = __builtin_amdgcn_mfma_f32_16x16x32_bf16(
                    Af[kk], Bf[tc][kk], acc[tc], 0, 0, 0);

        #pragma unroll
        for (int tc = 0; tc < 2; ++tc) {
            const int c = n0 + tc * 16 + l15;
            #pragma unroll
            for (int reg = 0; reg < 4; ++reg) {
                const int rl = rt * 16 + quad * 4 + reg;
                if (rl < nrows) {
                    const int r = r0 + rl;
                    if (done)
                        __hip_atomic_store(&dst[(size_t)r * dst_stride + dst_col + c],
                                           acc[tc][reg],
                                           __ATOMIC_RELAXED, __HIP_MEMORY_SCOPE_AGENT);
                    else
                        dst[(size_t)r * dst_stride + dst_col + c] = acc[tc][reg];
                }
            }
        }
    }

    if (done) {
        __syncthreads();   // drains vmcnt -> all xp0 stores of this block retired
        if (tid == 0)
            __hip_atomic_store(&done[done_idx], MAGIC,
                               __ATOMIC_RELEASE, __HIP_MEMORY_SCOPE_AGENT);
    }
}

// ---------------------------------------------------------------------------
// Single dispatch, 4 roles: 0..7 producers (rec0, publishes h0 chunks),
// 8..15 consumers (rec1, reads xp1 from dead-xp0 cells), 16..23 fusers
// (xp1 = h0 @ Wi1^T + b1 in place), 24..343 proj0 blocks (windows
// {8,24,32,32,32} rows/batch; w=0 first for a short producer prologue stall).
// ---------------------------------------------------------------------------
__global__ __launch_bounds__(512, 1)
void ltc_all(const int* __restrict__ tokens, const float* __restrict__ emb,
             const float* __restrict__ Wi0, const float* __restrict__ b0v,
             const float* __restrict__ Wr0, const float* __restrict__ m0,
             const float* __restrict__ t0v,
             const float* __restrict__ Wi1, const float* __restrict__ b1v,
             const float* __restrict__ Wr1, const float* __restrict__ m1,
             const float* __restrict__ t1v,
             float* out,
             unsigned int* flagsP, unsigned int* flagsF, unsigned int* projf)
{
    __shared__ __align__(16) ushort_t smem[64][LP];   // 33792 B, role-shared
    if (blockIdx.x < 8)
        scan_core<true, false>(blockIdx.x, (ushort_t(*)[4096])&smem[0][0],
                               out, OW_, H_,     // xp0 in out cols 256..511
                               out, 0,           // h0 -> cols 0..255 (agent)
                               Wr0, m0, t0v, flagsP + blockIdx.x, projf);
    else if (blockIdx.x < 16)
        scan_core<false, true>(blockIdx.x - 8, (ushort_t(*)[4096])&smem[0][0],
                               out, OW_, H_,     // xp1 from dead-xp0 cells
                               out, H_,          // h1 -> cols 256..511
                               Wr1, m1, t1v, flagsF + (blockIdx.x - 8), nullptr);
    else if (blockIdx.x < 24)
        fuser_core(blockIdx.x - 16, smem, out, Wi1, b1v,
                   flagsP + (blockIdx.x - 16), flagsF + (blockIdx.x - 16));
    else {
        const int p = blockIdx.x - 24;
        const int w = p >> 6, b = p & 63;
        const int r0 = b * T_ + (w == 0 ? 0 : (w == 1 ? 8 : 32 * (w - 1)));
        const int nr = (w == 0 ? 8 : (w == 1 ? 24 : 32));
        proj_body((ushort_t(*)[LP])smem, r0, nr, emb, E_, 0, tokens,
                  Wi0, b0v, out, OW_, H_, projf, p);
    }
}

// ---------------------------------------------------------------------------
// Fallback path (ws too small): sequential proj + standalone scans (proven).
// ---------------------------------------------------------------------------
__global__ __launch_bounds__(512, 1)
void ltc_single(const float* xp, int xp_stride, int xp_col,
                float* hout, int out_col,
                const float* __restrict__ Wr, const float* __restrict__ mk,
                const float* __restrict__ tu)
{
    __shared__ __align__(16) ushort_t hb[2][4096];
    scan_core<false, false>(blockIdx.x, hb, xp, xp_stride, xp_col,
                            hout, out_col, Wr, mk, tu, nullptr, nullptr);
}

__global__ __launch_bounds__(512, 2)
void proj_mfma(const float* __restrict__ src, int src_stride, int src_col,
               const int* __restrict__ tok,
               const float* __restrict__ Wi,
               const float* __restrict__ bias,
               float* __restrict__ dst, int dst_stride, int dst_col)
{
    __shared__ __align__(16) ushort_t As[32][LP];
    proj_body(As, blockIdx.x * 32, 32, src, src_stride, src_col, tok, Wi, bias,
              dst, dst_stride, dst_col, nullptr, 0);
}

extern "C" void kernel_launch(void* const* d_in, const int* in_sizes, int n_in,
                              void* d_out, int out_size, void* d_ws, size_t ws_size,
                              hipStream_t stream)
{
    const int*   tokens = (const int*)d_in[0];
    const float* emb    = (const float*)d_in[1];
    const float* W_in0  = (const float*)d_in[2];
    const float* W_rec0 = (const float*)d_in[3];
    const float* b0     = (const float*)d_in[4];
    const float* tau0   = (const float*)d_in[5];
    const float* mask0  = (const float*)d_in[6];
    const float* W_in1  = (const float*)d_in[7];
    const float* W_rec1 = (const float*)d_in[8];
    const float* b1     = (const float*)d_in[9];
    const float* tau1   = (const float*)d_in[10];
    const float* mask1  = (const float*)d_in[11];
    float* out = (float*)d_out;    // [8192, 512] f32
    (void)in_sizes; (void)n_in; (void)out_size;

    // ws: [flagsP (64B) | flagsF (64B) | projf (320*4B)] -- 1.4 KB total.
    const size_t need = 64 + 64 + 320 * sizeof(unsigned int);

    if (ws_size >= need) {
        // all flags arrive poisoned (0xAA..) each launch -> not-ready; the
        // window checks (==MAGIC / MAGIC+c in [1,16]) treat poison as unset.
        unsigned int* flagsP = (unsigned int*)d_ws;
        unsigned int* flagsF = (unsigned int*)((char*)d_ws + 64);
        unsigned int* projf  = (unsigned int*)((char*)d_ws + 128);
        ltc_all<<<dim3(344), dim3(512), 0, stream>>>(
            tokens, emb, W_in0, b0, W_rec0, mask0, tau0,
            W_in1, b1, W_rec1, mask1, tau1, out, flagsP, flagsF, projf);
    } else {
        proj_mfma<<<dim3(256), dim3(512), 0, stream>>>(
            emb, E_, 0, tokens, W_in0, b0, out, OW_, H_);
        ltc_single<<<dim3(8), dim3(512), 0, stream>>>(
            out, OW_, H_, out, 0, W_rec0, mask0, tau0);
        proj_mfma<<<dim3(256), dim3(512), 0, stream>>>(
            out, OW_, 0, nullptr, W_in1, b1, out, OW_, H_);
        ltc_single<<<dim3(8), dim3(512), 0, stream>>>(
            out, OW_, H_, out, H_, W_rec1, mask1, tau1);
    }
}